// Round 7
// baseline (471.762 us; speedup 1.0000x reference)
//
#include <hip/hip_runtime.h>
#include <math.h>

#define DQ 2048
#define CDIM 512
#define NKEYS 256
#define KSEL 32

__device__ __forceinline__ bool rank_before(float as, int ai, float bs, int bi) {
  return (as > bs) || (as == bs && ai < bi);
}
static __device__ __forceinline__ float bf2f(unsigned int u) {
  union { unsigned int i; float f; } v; v.i = u << 16; return v.f;
}
static __device__ __forceinline__ unsigned int f2bf(float f) {
  union { float f; unsigned int i; } v; v.f = f;
  unsigned int r = v.i + 0x7fffu + ((v.i >> 16) & 1u);
  return r >> 16;
}
// fp32 <-> descending-orderable uint32 (bijective; uint desc == float desc)
static __device__ __forceinline__ unsigned int f2ord(float f) {
  unsigned int b = __float_as_uint(f);
  return b ^ (unsigned int)(((int)b >> 31) | (int)0x80000000);
}
static __device__ __forceinline__ float ord2f(unsigned int u) {
  unsigned int b = u ^ (unsigned int)(((int)(~u) >> 31) | (int)0x80000000);
  return __uint_as_float(b);
}

// ---------------- q = LN(X * Wq^T) fused (fp32 vector GEMM + groupwise LN) ----------------
__global__ __launch_bounds__(256) void qgemm_ln(
    const float* __restrict__ X, const float* __restrict__ W,
    const float* __restrict__ gamma, const float* __restrict__ beta,
    float* __restrict__ Q) {
  __shared__ float As[16 * 68];   // [k][m]
  __shared__ float Bs[16 * 132];  // [k][n]
  const int tid = threadIdx.x;
  const int m0 = blockIdx.x * 64, n0 = blockIdx.y * 128;
  const int tx = tid & 15, ty = tid >> 4;
  const int am = tid >> 2, ak = (tid & 3) * 4;
  const int bn = tid >> 1, bk = (tid & 1) * 8;
  float acc[4][8] = {};
  // software prefetch of first tile
  float4 av  = *(const float4*)&X[(size_t)(m0 + am) * CDIM + ak];
  float4 bv0 = *(const float4*)&W[(size_t)(n0 + bn) * CDIM + bk];
  float4 bv1 = *(const float4*)&W[(size_t)(n0 + bn) * CDIM + bk + 4];
  for (int kt = 0; kt < CDIM; kt += 16) {
    __syncthreads();
    As[(ak + 0) * 68 + am] = av.x; As[(ak + 1) * 68 + am] = av.y;
    As[(ak + 2) * 68 + am] = av.z; As[(ak + 3) * 68 + am] = av.w;
    Bs[(bk + 0) * 132 + bn] = bv0.x; Bs[(bk + 1) * 132 + bn] = bv0.y;
    Bs[(bk + 2) * 132 + bn] = bv0.z; Bs[(bk + 3) * 132 + bn] = bv0.w;
    Bs[(bk + 4) * 132 + bn] = bv1.x; Bs[(bk + 5) * 132 + bn] = bv1.y;
    Bs[(bk + 6) * 132 + bn] = bv1.z; Bs[(bk + 7) * 132 + bn] = bv1.w;
    __syncthreads();
    if (kt + 16 < CDIM) {  // prefetch next tile; latency hides behind compute
      av  = *(const float4*)&X[(size_t)(m0 + am) * CDIM + kt + 16 + ak];
      bv0 = *(const float4*)&W[(size_t)(n0 + bn) * CDIM + kt + 16 + bk];
      bv1 = *(const float4*)&W[(size_t)(n0 + bn) * CDIM + kt + 16 + bk + 4];
    }
    #pragma unroll
    for (int kk = 0; kk < 16; ++kk) {
      float4 a4  = *(const float4*)&As[kk * 68 + ty * 4];
      float4 b4a = *(const float4*)&Bs[kk * 132 + tx * 8];
      float4 b4b = *(const float4*)&Bs[kk * 132 + tx * 8 + 4];
      const float ar[4] = {a4.x, a4.y, a4.z, a4.w};
      const float br[8] = {b4a.x, b4a.y, b4a.z, b4a.w, b4b.x, b4b.y, b4b.z, b4b.w};
      #pragma unroll
      for (int i = 0; i < 4; ++i)
        #pragma unroll
        for (int j = 0; j < 8; ++j)
          acc[i][j] += ar[i] * br[j];
    }
  }
  float g[8], bta[8];
  #pragma unroll
  for (int j = 0; j < 8; ++j) { g[j] = gamma[tx * 8 + j]; bta[j] = beta[tx * 8 + j]; }
  #pragma unroll
  for (int i = 0; i < 4; ++i) {
    float s = 0.f, sq = 0.f;
    #pragma unroll
    for (int j = 0; j < 8; ++j) { s += acc[i][j]; sq += acc[i][j] * acc[i][j]; }
    #pragma unroll
    for (int m = 1; m < 16; m <<= 1) {
      s += __shfl_xor(s, m, 64);
      sq += __shfl_xor(sq, m, 64);
    }
    float mean = s * (1.0f / 128.0f);
    float var = sq * (1.0f / 128.0f) - mean * mean;
    float rs = 1.0f / sqrtf(var + 1e-5f);
    float o[8];
    #pragma unroll
    for (int j = 0; j < 8; ++j) o[j] = (acc[i][j] - mean) * rs * g[j] + bta[j];
    float* dst = &Q[(size_t)(m0 + ty * 4 + i) * DQ + n0 + tx * 8];
    *(float4*)dst = make_float4(o[0], o[1], o[2], o[3]);
    *(float4*)(dst + 4) = make_float4(o[4], o[5], o[6], o[7]);
  }
}

// ---------------- keys[h][n][p][d] -> keysT[hp][d][n] (one-time, 2 MB) ----------------
__global__ __launch_bounds__(256) void transpose_keys(
    const float* __restrict__ keys, float* __restrict__ keysT) {
  __shared__ float tile[64 * 129];
  const int hp = blockIdx.x, h = hp >> 1, p = hp & 1;
  const int n0 = blockIdx.y * 64;
  {
    const int n = threadIdx.x >> 2;          // 0..63
    const int d0 = (threadIdx.x & 3) * 32;   // 0,32,64,96
    const float* src = &keys[(((size_t)h * NKEYS + n0 + n) * 2 + p) * 128 + d0];
    #pragma unroll
    for (int j = 0; j < 32; j += 4) {
      float4 v = *(const float4*)(src + j);
      tile[n * 129 + d0 + j + 0] = v.x;
      tile[n * 129 + d0 + j + 1] = v.y;
      tile[n * 129 + d0 + j + 2] = v.z;
      tile[n * 129 + d0 + j + 3] = v.w;
    }
  }
  __syncthreads();
  {
    const int d = threadIdx.x >> 1;          // 0..127
    const int nh = (threadIdx.x & 1) * 32;   // 0,32
    float* dst = &keysT[((size_t)hp * 128 + d) * NKEYS + n0 + nh];
    #pragma unroll
    for (int j = 0; j < 32; j += 4) {
      float4 o = make_float4(tile[(nh + j + 0) * 129 + d], tile[(nh + j + 1) * 129 + d],
                             tile[(nh + j + 2) * 129 + d], tile[(nh + j + 3) * 129 + d]);
      *(float4*)(dst + j) = o;
    }
  }
}

// ---------------- dots + 4-way-interleaved KEY-ONLY bitonic top-32 ----------------
// Round-7 = round-6 with the writelane builtin (not available on this hipcc)
// replaced by a predicated move: idj is wave-uniform and j is compile-time, so
// `if (lane == (j>>2)) idX = idj;` lowers to one v_cndmask -- same semantics.
// Scores are transformed to orderable uint32 (bijective -> bit-exact output);
// the bitonic network shuffles ONLY the 32-bit key (DS ops 672 -> 336/wave,
// 4 independent shuffle chains). Ids recovered post-sort by readlane + 4
// ballot-equality matches + ffs; used-bit mask gives duplicate scores
// successively increasing ids == top_k's (score desc, id asc) tie order.
// GEMM phase: A uniform via readfirstlane -> s_load; B coalesced from keysT,
// L2-hot; zero LDS, zero barriers.
__global__ __launch_bounds__(512, 5) void dots_sel(
    const float* __restrict__ Q, const float* __restrict__ keysT,
    float* __restrict__ s1s, int* __restrict__ s1i) {
  const int hp = blockIdx.x;
  const int chunk = blockIdx.y;
  const int h = hp >> 1, p = hp & 1;
  const int t0 = chunk * 32;
  const int tid = threadIdx.x;
  const int w = tid >> 6, lane = tid & 63;
  // wave-uniform Q row pointers (readfirstlane -> provably uniform -> SMEM)
  const int wu = __builtin_amdgcn_readfirstlane(w);
  const float* q0 = &Q[(size_t)(t0 + wu * 4 + 0) * DQ + p * 1024 + h * 128];
  const float* q1 = q0 + DQ;
  const float* q2 = q0 + 2 * DQ;
  const float* q3 = q0 + 3 * DQ;
  const float* kT = keysT + (size_t)hp * 128 * NKEYS + lane * 4;
  float acc[4][4] = {};
  #pragma unroll 2
  for (int kt = 0; kt < 128; kt += 4) {
    float4 a0 = *(const float4*)&q0[kt];
    float4 a1 = *(const float4*)&q1[kt];
    float4 a2 = *(const float4*)&q2[kt];
    float4 a3 = *(const float4*)&q3[kt];
    const float a0r[4] = {a0.x, a0.y, a0.z, a0.w};
    const float a1r[4] = {a1.x, a1.y, a1.z, a1.w};
    const float a2r[4] = {a2.x, a2.y, a2.z, a2.w};
    const float a3r[4] = {a3.x, a3.y, a3.z, a3.w};
    #pragma unroll
    for (int kk = 0; kk < 4; ++kk) {
      float4 b4 = *(const float4*)&kT[(size_t)(kt + kk) * NKEYS];
      const float br[4] = {b4.x, b4.y, b4.z, b4.w};
      #pragma unroll
      for (int j = 0; j < 4; ++j) {
        acc[0][j] += a0r[kk] * br[j];
        acc[1][j] += a1r[kk] * br[j];
        acc[2][j] += a2r[kk] * br[j];
        acc[3][j] += a3r[kk] * br[j];
      }
    }
  }
  // ---- transform to orderable keys; keep originals for id recovery
  unsigned int ts[4][4], tso[4][4];
  #pragma unroll
  for (int t = 0; t < 4; ++t)
    #pragma unroll
    for (int r = 0; r < 4; ++r) {
      unsigned int b = f2ord(acc[t][r]);
      ts[t][r] = b; tso[t][r] = b;
    }

  // ---- key-only bitonic-256, identical network structure to the verified
  // rank_before version; comparator semantics: dd=false -> a=max (descending),
  // cross: flip -> keep min else keep max. Equal keys: either kept, identical.
  #define CES(a, b, dd)                                                        \
    {                                                                          \
      _Pragma("unroll")                                                        \
      for (int t_ = 0; t_ < 4; ++t_) {                                         \
        unsigned int x_ = ts[t_][a], y_ = ts[t_][b];                           \
        unsigned int lo_ = x_ < y_ ? x_ : y_;                                  \
        unsigned int hi_ = x_ < y_ ? y_ : x_;                                  \
        ts[t_][a] = (dd) ? lo_ : hi_;                                          \
        ts[t_][b] = (dd) ? hi_ : lo_;                                          \
      }                                                                        \
    }
  #define XRS(L, dd)                                                           \
    {                                                                          \
      const bool flip_ = (((lane & (L)) != 0) != (dd));                        \
      _Pragma("unroll")                                                        \
      for (int t_ = 0; t_ < 4; ++t_)                                           \
        _Pragma("unroll")                                                      \
        for (int r_ = 0; r_ < 4; ++r_) {                                       \
          unsigned int o_ = __shfl_xor(ts[t_][r_], (L), 64);                   \
          bool take_ = ((o_ > ts[t_][r_]) != flip_);                           \
          if (take_) ts[t_][r_] = o_;                                          \
        }                                                                      \
    }
  CES(0, 1, false); CES(2, 3, true);
  {
    bool dd = (lane & 1) != 0;
    CES(0, 2, dd); CES(1, 3, dd); CES(0, 1, dd); CES(2, 3, dd);
  }
  #pragma unroll
  for (int K = 8; K <= 256; K <<= 1) {
    bool dd = (lane & (K >> 2)) != 0;
    #pragma unroll
    for (int L = K >> 3; L >= 1; L >>= 1) XRS(L, dd);
    CES(0, 2, dd); CES(1, 3, dd); CES(0, 1, dd); CES(2, 3, dd);
  }
  #undef CES
  #undef XRS

  // ---- id recovery + output: winners are positions 0..31 = lanes 0..7, r 0..3
  #pragma unroll
  for (int t = 0; t < 4; ++t) {
    unsigned long long us0 = 0, us1 = 0, us2 = 0, us3 = 0;
    unsigned int prevw = 0u;
    int id0 = 0, id1 = 0, id2 = 0, id3 = 0;
    #pragma unroll
    for (int j = 0; j < 32; ++j) {
      unsigned int tw;
      if ((j & 3) == 0)      tw = (unsigned int)__builtin_amdgcn_readlane((int)ts[t][0], j >> 2);
      else if ((j & 3) == 1) tw = (unsigned int)__builtin_amdgcn_readlane((int)ts[t][1], j >> 2);
      else if ((j & 3) == 2) tw = (unsigned int)__builtin_amdgcn_readlane((int)ts[t][2], j >> 2);
      else                   tw = (unsigned int)__builtin_amdgcn_readlane((int)ts[t][3], j >> 2);
      const bool same = (j != 0) && (tw == prevw);  // duplicate run -> exclude used ids
      us0 = same ? us0 : 0ull; us1 = same ? us1 : 0ull;
      us2 = same ? us2 : 0ull; us3 = same ? us3 : 0ull;
      unsigned long long b0 = __ballot(tso[t][0] == tw) & ~us0;
      unsigned long long b1 = __ballot(tso[t][1] == tw) & ~us1;
      unsigned long long b2 = __ballot(tso[t][2] == tw) & ~us2;
      unsigned long long b3 = __ballot(tso[t][3] == tw) & ~us3;
      unsigned long long mu = b0 | b1 | b2 | b3;
      const int Lw = __ffsll((unsigned long long)mu) - 1;  // lowest matching lane
      const unsigned long long bit = 1ull << Lw;
      const int rr = (b0 & bit) ? 0 : (b1 & bit) ? 1 : (b2 & bit) ? 2 : 3;
      us0 |= (rr == 0) ? bit : 0ull; us1 |= (rr == 1) ? bit : 0ull;
      us2 |= (rr == 2) ? bit : 0ull; us3 |= (rr == 3) ? bit : 0ull;
      const int idj = (Lw << 2) | rr;  // lowest id matching this score (wave-uniform)
      if (lane == (j >> 2)) {          // predicated move == writelane (j compile-time)
        if ((j & 3) == 0)      id0 = idj;
        else if ((j & 3) == 1) id1 = idj;
        else if ((j & 3) == 2) id2 = idj;
        else                   id3 = idj;
      }
      prevw = tw;
    }
    if (lane < 8) {
      const int inst = (t0 + w * 4 + t) * 16 + hp;
      *(float4*)&s1s[(size_t)inst * KSEL + lane * 4] =
          make_float4(ord2f(ts[t][0]), ord2f(ts[t][1]), ord2f(ts[t][2]), ord2f(ts[t][3]));
      *(int4*)&s1i[(size_t)inst * KSEL + lane * 4] = make_int4(id0, id1, id2, id3);
    }
  }
}

// ---------------- stage-2: pruned 119-candidate bitonic top-32 + softmax ----------------
__constant__ unsigned short slot_ij[128] = {
  0,1,2,3,4,5,6,7,8,9,10,11,12,13,14,15,16,17,18,19,20,21,22,23,24,25,26,27,28,29,30,31,
  32,33,34,35,36,37,38,39,40,41,42,43,44,45,46,47,
  64,65,66,67,68,69,70,71,72,73,
  96,97,98,99,100,101,102,103,
  128,129,130,131,132,133,
  160,161,162,163,164,
  192,193,194,195,
  224,225,226,227,
  256,257,258,
  288,289,290,
  320,321, 352,353, 384,385, 416,417, 448,449, 480,481,
  512,544,576,608,640,672,704,736,768,800,832,864,896,928,960,992,
  0xFFFF,0xFFFF,0xFFFF,0xFFFF,0xFFFF,0xFFFF,0xFFFF,0xFFFF,0xFFFF
};

__global__ __launch_bounds__(256) void stage2_kernel(
    const float* __restrict__ s1s, const int* __restrict__ s1i,
    float* __restrict__ wgt, int* __restrict__ vidx) {
  const int th = blockIdx.x * 4 + (threadIdx.x >> 6);
  const int lane = threadIdx.x & 63;
  const int bx = th * 64;
  const int by = bx + 32;
  float s[2]; int id[2];
  #pragma unroll
  for (int r = 0; r < 2; ++r) {
    int sl = slot_ij[lane * 2 + r];
    if (sl != 0xFFFF) {
      s[r] = s1s[bx + (sl >> 5)] + s1s[by + (sl & 31)];
      id[r] = sl;
    } else {
      s[r] = -INFINITY; id[r] = 0x7fffffff;
    }
  }
  #define CE2(dd)                                                              \
    {                                                                          \
      bool sw = (dd) ? rank_before(s[0], id[0], s[1], id[1])                   \
                     : rank_before(s[1], id[1], s[0], id[0]);                  \
      if (sw) {                                                                \
        float ts = s[0]; s[0] = s[1]; s[1] = ts;                               \
        int ti = id[0]; id[0] = id[1]; id[1] = ti;                             \
      }                                                                        \
    }
  #define CROSS2(L, dd)                                                        \
    {                                                                          \
      bool amHigh = (lane & (L)) != 0;                                         \
      bool flip = amHigh != (dd);                                              \
      _Pragma("unroll")                                                        \
      for (int r = 0; r < 2; ++r) {                                            \
        float os = __shfl_xor(s[r], (L), 64);                                  \
        int oi = __shfl_xor(id[r], (L), 64);                                   \
        bool take = rank_before(os, oi, s[r], id[r]) != flip;                  \
        if (take) { s[r] = os; id[r] = oi; }                                   \
      }                                                                        \
    }
  { bool dd = (lane & 1) != 0; CE2(dd); }
  #pragma unroll
  for (int K = 4; K <= 128; K <<= 1) {
    bool dd = (lane & (K >> 1)) != 0;
    #pragma unroll
    for (int L = K >> 2; L >= 1; L >>= 1) CROSS2(L, dd);
    CE2(dd);
  }
  #undef CE2
  #undef CROSS2
  float smax = __shfl(s[0], 0, 64);
  float e0 = 0.f, e1 = 0.f;
  if (lane < 16) { e0 = expf(s[0] - smax); e1 = expf(s[1] - smax); }
  float part = e0 + e1;
  #pragma unroll
  for (int m = 1; m < 16; m <<= 1) part += __shfl_xor(part, m, 64);
  if (lane < 16) {
    int f0 = id[0], f1 = id[1];
    int vi0 = s1i[bx + (f0 >> 5)] * NKEYS + s1i[by + (f0 & 31)];
    int vi1 = s1i[bx + (f1 >> 5)] * NKEYS + s1i[by + (f1 & 31)];
    wgt[(size_t)th * KSEL + lane * 2] = e0 / part;
    wgt[(size_t)th * KSEL + lane * 2 + 1] = e1 / part;
    vidx[(size_t)th * KSEL + lane * 2] = vi0;
    vidx[(size_t)th * KSEL + lane * 2 + 1] = vi1;
  }
}

// ---------------- values fp32 -> bf16 (RNE) one-pass convert ----------------
__global__ __launch_bounds__(256) void convert_values(
    const float* __restrict__ values, unsigned int* __restrict__ vbf) {
  const size_t g = ((size_t)blockIdx.x * 256 + threadIdx.x) * 8;
  float4 a = *(const float4*)(values + g);
  float4 b = *(const float4*)(values + g + 4);
  uint4 pk;
  pk.x = f2bf(a.x) | (f2bf(a.y) << 16);
  pk.y = f2bf(a.z) | (f2bf(a.w) << 16);
  pk.z = f2bf(b.x) | (f2bf(b.y) << 16);
  pk.w = f2bf(b.z) | (f2bf(b.w) << 16);
  *(uint4*)(vbf + g / 2) = pk;
}

// ---------------- gather bf16: wave-per-row, 4 L3 phases ----------------
__global__ __launch_bounds__(256) void gather_bf16(
    const float* __restrict__ wgt, const int* __restrict__ vidx,
    const unsigned short* __restrict__ vbf, float* __restrict__ out) {
  const int t = blockIdx.x;
  const int tid = threadIdx.x, w = tid >> 6, lane = tid & 63;
  __shared__ float ws_[256];
  __shared__ int vs_[256];
  __shared__ float part[4 * 520];
  ws_[tid] = wgt[(size_t)t * 256 + tid];
  vs_[tid] = vidx[(size_t)t * 256 + tid];
  __syncthreads();
  float acc[8] = {};
  const int c0 = lane * 8;
  #pragma unroll 1
  for (int phase = 0; phase < 4; ++phase) {
    for (int e = w; e < 256; e += 4) {
      const int row = vs_[e];                 // wave-uniform scalar
      if ((row >> 14) != phase) continue;     // uniform branch, no divergence
      const float wv = ws_[e];
      uint4 pk = *(const uint4*)(vbf + (size_t)row * CDIM + c0);
      acc[0] += wv * bf2f(pk.x & 0xffff); acc[1] += wv * bf2f(pk.x >> 16);
      acc[2] += wv * bf2f(pk.y & 0xffff); acc[3] += wv * bf2f(pk.y >> 16);
      acc[4] += wv * bf2f(pk.z & 0xffff); acc[5] += wv * bf2f(pk.z >> 16);
      acc[6] += wv * bf2f(pk.w & 0xffff); acc[7] += wv * bf2f(pk.w >> 16);
    }
  }
  #pragma unroll
  for (int j = 0; j < 8; j += 4)
    *(float4*)&part[w * 520 + c0 + j] =
        make_float4(acc[j], acc[j + 1], acc[j + 2], acc[j + 3]);
  __syncthreads();
  const int c2 = tid * 2;
  float r0 = part[c2] + part[520 + c2] + part[1040 + c2] + part[1560 + c2];
  float r1 = part[c2 + 1] + part[520 + c2 + 1] + part[1040 + c2 + 1] + part[1560 + c2 + 1];
  *(float2*)(out + (size_t)t * CDIM + c2) = make_float2(r0, r1);
}

// ---------------- fallback fp32 gather (round-4, for small ws) ----------------
__global__ __launch_bounds__(256) void gather_kernel(
    const float* __restrict__ wgt, const int* __restrict__ vidx,
    const float* __restrict__ values, float* __restrict__ out) {
  const int tp = blockIdx.x;
  const int tid = threadIdx.x;
  __shared__ float ws_[512];
  __shared__ int vs_[512];
  ws_[tid] = wgt[(size_t)tp * 512 + tid];
  ws_[tid + 256] = wgt[(size_t)tp * 512 + tid + 256];
  vs_[tid] = vidx[(size_t)tp * 512 + tid];
  vs_[tid + 256] = vidx[(size_t)tp * 512 + tid + 256];
  __syncthreads();
  const int sub = tid >> 7;
  const int c4 = (tid & 127) * 4;
  const float* wp = &ws_[sub * 256];
  const int* vp = &vs_[sub * 256];
  float4 a = make_float4(0.f, 0.f, 0.f, 0.f);
  #pragma unroll 4
  for (int e = 0; e < 256; ++e) {
    float4 vv = *(const float4*)(values + (size_t)vp[e] * CDIM + c4);
    float wv = wp[e];
    a.x += wv * vv.x; a.y += wv * vv.y; a.z += wv * vv.z; a.w += wv * vv.w;
  }
  *(float4*)(out + (size_t)(tp * 2 + sub) * CDIM + c4) = a;
}

extern "C" void kernel_launch(void* const* d_in, const int* in_sizes, int n_in,
                              void* d_out, int out_size, void* d_ws, size_t ws_size,
                              hipStream_t stream) {
  const float* X      = (const float*)d_in[0];
  const float* W      = (const float*)d_in[1];
  const float* keys   = (const float*)d_in[2];
  const float* values = (const float*)d_in[3];
  const float* gamma  = (const float*)d_in[4];
  const float* beta   = (const float*)d_in[5];
  char* ws = (char*)d_ws;
  float* s1s = (float*)(ws);                  // 0..4 MB
  int*   s1i = (int*)  (ws + (4u << 20));     // 4..8 MB
  float* wgt = (float*)(ws + (8u << 20));     // 8..10 MB
  int*   vix = (int*)  (ws + (10u << 20));    // 10..12 MB
  float* Q   = (float*)(ws + (12u << 20));    // 12..28 MB (dead after dots_sel)
  float* kT  = (float*)(ws + (28u << 20));    // 28..30 MB (dead after dots_sel)
  unsigned int* vbf = (unsigned int*)(ws + (12u << 20));  // 12..76 MB (overlaps dead Q+kT)

  const bool bf16_path = ws_size >= (76u << 20);

  transpose_keys<<<dim3(16, 4), 256, 0, stream>>>(keys, kT);
  qgemm_ln<<<dim3(32, 16), 256, 0, stream>>>(X, W, gamma, beta, Q);
  dots_sel<<<dim3(16, 64), 512, 0, stream>>>(Q, kT, s1s, s1i);
  stage2_kernel<<<4096, 256, 0, stream>>>(s1s, s1i, wgt, vix);
  if (bf16_path) {
    convert_values<<<16384, 256, 0, stream>>>(values, vbf);  // after dots_sel: Q,kT dead
    gather_bf16<<<2048, 256, 0, stream>>>(wgt, vix, (const unsigned short*)vbf, (float*)d_out);
  } else {
    gather_kernel<<<1024, 256, 0, stream>>>(wgt, vix, values, (float*)d_out);
  }
}

// Round 8
// 460.416 us; speedup vs baseline: 1.0246x; 1.0246x over previous
//
#include <hip/hip_runtime.h>
#include <math.h>

#define DQ 2048
#define CDIM 512
#define NKEYS 256
#define KSEL 32

__device__ __forceinline__ bool rank_before(float as, int ai, float bs, int bi) {
  return (as > bs) || (as == bs && ai < bi);
}
static __device__ __forceinline__ float bf2f(unsigned int u) {
  union { unsigned int i; float f; } v; v.i = u << 16; return v.f;
}
static __device__ __forceinline__ unsigned int f2bf(float f) {
  union { float f; unsigned int i; } v; v.f = f;
  unsigned int r = v.i + 0x7fffu + ((v.i >> 16) & 1u);
  return r >> 16;
}

// ---------------- q = LN(X * Wq^T) fused (fp32 vector GEMM + groupwise LN) ----------------
__global__ __launch_bounds__(256) void qgemm_ln(
    const float* __restrict__ X, const float* __restrict__ W,
    const float* __restrict__ gamma, const float* __restrict__ beta,
    float* __restrict__ Q) {
  __shared__ float As[16 * 68];   // [k][m]
  __shared__ float Bs[16 * 132];  // [k][n]
  const int tid = threadIdx.x;
  const int m0 = blockIdx.x * 64, n0 = blockIdx.y * 128;
  const int tx = tid & 15, ty = tid >> 4;
  const int am = tid >> 2, ak = (tid & 3) * 4;
  const int bn = tid >> 1, bk = (tid & 1) * 8;
  float acc[4][8] = {};
  // software prefetch of first tile
  float4 av  = *(const float4*)&X[(size_t)(m0 + am) * CDIM + ak];
  float4 bv0 = *(const float4*)&W[(size_t)(n0 + bn) * CDIM + bk];
  float4 bv1 = *(const float4*)&W[(size_t)(n0 + bn) * CDIM + bk + 4];
  for (int kt = 0; kt < CDIM; kt += 16) {
    __syncthreads();
    As[(ak + 0) * 68 + am] = av.x; As[(ak + 1) * 68 + am] = av.y;
    As[(ak + 2) * 68 + am] = av.z; As[(ak + 3) * 68 + am] = av.w;
    Bs[(bk + 0) * 132 + bn] = bv0.x; Bs[(bk + 1) * 132 + bn] = bv0.y;
    Bs[(bk + 2) * 132 + bn] = bv0.z; Bs[(bk + 3) * 132 + bn] = bv0.w;
    Bs[(bk + 4) * 132 + bn] = bv1.x; Bs[(bk + 5) * 132 + bn] = bv1.y;
    Bs[(bk + 6) * 132 + bn] = bv1.z; Bs[(bk + 7) * 132 + bn] = bv1.w;
    __syncthreads();
    if (kt + 16 < CDIM) {  // prefetch next tile; latency hides behind compute
      av  = *(const float4*)&X[(size_t)(m0 + am) * CDIM + kt + 16 + ak];
      bv0 = *(const float4*)&W[(size_t)(n0 + bn) * CDIM + kt + 16 + bk];
      bv1 = *(const float4*)&W[(size_t)(n0 + bn) * CDIM + kt + 16 + bk + 4];
    }
    #pragma unroll
    for (int kk = 0; kk < 16; ++kk) {
      float4 a4  = *(const float4*)&As[kk * 68 + ty * 4];
      float4 b4a = *(const float4*)&Bs[kk * 132 + tx * 8];
      float4 b4b = *(const float4*)&Bs[kk * 132 + tx * 8 + 4];
      const float ar[4] = {a4.x, a4.y, a4.z, a4.w};
      const float br[8] = {b4a.x, b4a.y, b4a.z, b4a.w, b4b.x, b4b.y, b4b.z, b4b.w};
      #pragma unroll
      for (int i = 0; i < 4; ++i)
        #pragma unroll
        for (int j = 0; j < 8; ++j)
          acc[i][j] += ar[i] * br[j];
    }
  }
  float g[8], bta[8];
  #pragma unroll
  for (int j = 0; j < 8; ++j) { g[j] = gamma[tx * 8 + j]; bta[j] = beta[tx * 8 + j]; }
  #pragma unroll
  for (int i = 0; i < 4; ++i) {
    float s = 0.f, sq = 0.f;
    #pragma unroll
    for (int j = 0; j < 8; ++j) { s += acc[i][j]; sq += acc[i][j] * acc[i][j]; }
    #pragma unroll
    for (int m = 1; m < 16; m <<= 1) {
      s += __shfl_xor(s, m, 64);
      sq += __shfl_xor(sq, m, 64);
    }
    float mean = s * (1.0f / 128.0f);
    float var = sq * (1.0f / 128.0f) - mean * mean;
    float rs = 1.0f / sqrtf(var + 1e-5f);
    float o[8];
    #pragma unroll
    for (int j = 0; j < 8; ++j) o[j] = (acc[i][j] - mean) * rs * g[j] + bta[j];
    float* dst = &Q[(size_t)(m0 + ty * 4 + i) * DQ + n0 + tx * 8];
    *(float4*)dst = make_float4(o[0], o[1], o[2], o[3]);
    *(float4*)(dst + 4) = make_float4(o[4], o[5], o[6], o[7]);
  }
}

// ---------------- keys[h][n][p][d] -> keysT[hp][d][n] (one-time, 2 MB) ----------------
__global__ __launch_bounds__(256) void transpose_keys(
    const float* __restrict__ keys, float* __restrict__ keysT) {
  __shared__ float tile[64 * 129];
  const int hp = blockIdx.x, h = hp >> 1, p = hp & 1;
  const int n0 = blockIdx.y * 64;
  {
    const int n = threadIdx.x >> 2;          // 0..63
    const int d0 = (threadIdx.x & 3) * 32;   // 0,32,64,96
    const float* src = &keys[(((size_t)h * NKEYS + n0 + n) * 2 + p) * 128 + d0];
    #pragma unroll
    for (int j = 0; j < 32; j += 4) {
      float4 v = *(const float4*)(src + j);
      tile[n * 129 + d0 + j + 0] = v.x;
      tile[n * 129 + d0 + j + 1] = v.y;
      tile[n * 129 + d0 + j + 2] = v.z;
      tile[n * 129 + d0 + j + 3] = v.w;
    }
  }
  __syncthreads();
  {
    const int d = threadIdx.x >> 1;          // 0..127
    const int nh = (threadIdx.x & 1) * 32;   // 0,32
    float* dst = &keysT[((size_t)hp * 128 + d) * NKEYS + n0 + nh];
    #pragma unroll
    for (int j = 0; j < 32; j += 4) {
      float4 o = make_float4(tile[(nh + j + 0) * 129 + d], tile[(nh + j + 1) * 129 + d],
                             tile[(nh + j + 2) * 129 + d], tile[(nh + j + 3) * 129 + d]);
      *(float4*)(dst + j) = o;
    }
  }
}

// ---------------- dots + 4-WAY interleaved bitonic top-32 (s+id payload) ----------------
// Round-8: revert to the proven round-5 payload sort (104 us) -- ballot-based
// id recovery (rounds 6-7) REGRESSED to 131 us: its 128-step readlane/ballot
// chain is serial and latency-bound. Do not revisit.
// Single change vs round 5: ALL FOUR token sorts run in one interleaved pass
// sequence (4 independent DS chains per wave instead of 2 serial pair-iters).
// Both pipes were ~55% busy (dependency-bound); deeper interleave raises
// utilization without changing comparator work.
// GEMM phase: A uniform via readfirstlane -> s_load; B coalesced from keysT,
// L2-hot; zero LDS, zero barriers. launch_bounds (512,5): VGPR cap ~102 for
// ~56-72 demand ((512,6)'s 80-cap demoted sort state to scratch in round 1).
__global__ __launch_bounds__(512, 5) void dots_sel(
    const float* __restrict__ Q, const float* __restrict__ keysT,
    float* __restrict__ s1s, int* __restrict__ s1i) {
  const int hp = blockIdx.x;
  const int chunk = blockIdx.y;
  const int h = hp >> 1, p = hp & 1;
  const int t0 = chunk * 32;
  const int tid = threadIdx.x;
  const int w = tid >> 6, lane = tid & 63;
  // wave-uniform Q row pointers (readfirstlane -> provably uniform -> SMEM)
  const int wu = __builtin_amdgcn_readfirstlane(w);
  const float* q0 = &Q[(size_t)(t0 + wu * 4 + 0) * DQ + p * 1024 + h * 128];
  const float* q1 = q0 + DQ;
  const float* q2 = q0 + 2 * DQ;
  const float* q3 = q0 + 3 * DQ;
  const float* kT = keysT + (size_t)hp * 128 * NKEYS + lane * 4;
  float acc[4][4] = {};
  #pragma unroll 2
  for (int kt = 0; kt < 128; kt += 4) {
    float4 a0 = *(const float4*)&q0[kt];
    float4 a1 = *(const float4*)&q1[kt];
    float4 a2 = *(const float4*)&q2[kt];
    float4 a3 = *(const float4*)&q3[kt];
    const float a0r[4] = {a0.x, a0.y, a0.z, a0.w};
    const float a1r[4] = {a1.x, a1.y, a1.z, a1.w};
    const float a2r[4] = {a2.x, a2.y, a2.z, a2.w};
    const float a3r[4] = {a3.x, a3.y, a3.z, a3.w};
    #pragma unroll
    for (int kk = 0; kk < 4; ++kk) {
      float4 b4 = *(const float4*)&kT[(size_t)(kt + kk) * NKEYS];
      const float br[4] = {b4.x, b4.y, b4.z, b4.w};
      #pragma unroll
      for (int j = 0; j < 4; ++j) {
        acc[0][j] += a0r[kk] * br[j];
        acc[1][j] += a1r[kk] * br[j];
        acc[2][j] += a2r[kk] * br[j];
        acc[3][j] += a3r[kk] * br[j];
      }
    }
  }
  // ---- 4-way interleaved in-register bitonic top-32 (4 concurrent sorts)
  #define CE1(S, I, a, b, dd)                                                  \
    {                                                                          \
      bool sw_ = (dd) ? rank_before(S[a], I[a], S[b], I[b])                    \
                      : rank_before(S[b], I[b], S[a], I[a]);                   \
      if (sw_) {                                                               \
        float ts_ = S[a]; S[a] = S[b]; S[b] = ts_;                             \
        int ti_ = I[a]; I[a] = I[b]; I[b] = ti_;                               \
      }                                                                        \
    }
  #define CEQ(a, b, dd)                                                        \
    { CE1(sA, iA, a, b, dd) CE1(sB, iB, a, b, dd)                              \
      CE1(sC, iC, a, b, dd) CE1(sD, iD, a, b, dd) }
  #define XCH1(S, I, r, L, flip)                                               \
    {                                                                          \
      float os_ = __shfl_xor(S[r], (L), 64);                                   \
      int oi_ = __shfl_xor(I[r], (L), 64);                                     \
      bool tk_ = rank_before(os_, oi_, S[r], I[r]) != (flip);                  \
      if (tk_) { S[r] = os_; I[r] = oi_; }                                     \
    }
  #define CROSSQ(L, dd)                                                        \
    {                                                                          \
      bool amHigh = (lane & (L)) != 0;                                         \
      bool flip = amHigh != (dd);                                              \
      _Pragma("unroll")                                                        \
      for (int r = 0; r < 4; ++r) {                                            \
        XCH1(sA, iA, r, L, flip) XCH1(sB, iB, r, L, flip)                      \
        XCH1(sC, iC, r, L, flip) XCH1(sD, iD, r, L, flip)                      \
      }                                                                        \
    }
  float sA[4], sB[4], sC[4], sD[4];
  int iA[4], iB[4], iC[4], iD[4];
  #pragma unroll
  for (int r = 0; r < 4; ++r) {
    sA[r] = acc[0][r]; sB[r] = acc[1][r];
    sC[r] = acc[2][r]; sD[r] = acc[3][r];
    iA[r] = iB[r] = iC[r] = iD[r] = lane * 4 + r;
  }
  CEQ(0, 1, false); CEQ(2, 3, true);
  {
    bool dd = (lane & 1) != 0;
    CEQ(0, 2, dd); CEQ(1, 3, dd); CEQ(0, 1, dd); CEQ(2, 3, dd);
  }
  #pragma unroll
  for (int K = 8; K <= 256; K <<= 1) {
    bool dd = (lane & (K >> 2)) != 0;
    #pragma unroll
    for (int L = K >> 3; L >= 1; L >>= 1) CROSSQ(L, dd);
    CEQ(0, 2, dd); CEQ(1, 3, dd); CEQ(0, 1, dd); CEQ(2, 3, dd);
  }
  #undef CE1
  #undef CEQ
  #undef XCH1
  #undef CROSSQ
  if (lane < 8) {
    const int inst0 = (t0 + w * 4 + 0) * 16 + hp;
    const int inst1 = inst0 + 16;
    const int inst2 = inst0 + 32;
    const int inst3 = inst0 + 48;
    *(float4*)&s1s[(size_t)inst0 * KSEL + lane * 4] = make_float4(sA[0], sA[1], sA[2], sA[3]);
    *(int4*)&s1i[(size_t)inst0 * KSEL + lane * 4] = make_int4(iA[0], iA[1], iA[2], iA[3]);
    *(float4*)&s1s[(size_t)inst1 * KSEL + lane * 4] = make_float4(sB[0], sB[1], sB[2], sB[3]);
    *(int4*)&s1i[(size_t)inst1 * KSEL + lane * 4] = make_int4(iB[0], iB[1], iB[2], iB[3]);
    *(float4*)&s1s[(size_t)inst2 * KSEL + lane * 4] = make_float4(sC[0], sC[1], sC[2], sC[3]);
    *(int4*)&s1i[(size_t)inst2 * KSEL + lane * 4] = make_int4(iC[0], iC[1], iC[2], iC[3]);
    *(float4*)&s1s[(size_t)inst3 * KSEL + lane * 4] = make_float4(sD[0], sD[1], sD[2], sD[3]);
    *(int4*)&s1i[(size_t)inst3 * KSEL + lane * 4] = make_int4(iD[0], iD[1], iD[2], iD[3]);
  }
}

// ---------------- stage-2: pruned 119-candidate bitonic top-32 + softmax ----------------
__constant__ unsigned short slot_ij[128] = {
  0,1,2,3,4,5,6,7,8,9,10,11,12,13,14,15,16,17,18,19,20,21,22,23,24,25,26,27,28,29,30,31,
  32,33,34,35,36,37,38,39,40,41,42,43,44,45,46,47,
  64,65,66,67,68,69,70,71,72,73,
  96,97,98,99,100,101,102,103,
  128,129,130,131,132,133,
  160,161,162,163,164,
  192,193,194,195,
  224,225,226,227,
  256,257,258,
  288,289,290,
  320,321, 352,353, 384,385, 416,417, 448,449, 480,481,
  512,544,576,608,640,672,704,736,768,800,832,864,896,928,960,992,
  0xFFFF,0xFFFF,0xFFFF,0xFFFF,0xFFFF,0xFFFF,0xFFFF,0xFFFF,0xFFFF
};

__global__ __launch_bounds__(256) void stage2_kernel(
    const float* __restrict__ s1s, const int* __restrict__ s1i,
    float* __restrict__ wgt, int* __restrict__ vidx) {
  const int th = blockIdx.x * 4 + (threadIdx.x >> 6);
  const int lane = threadIdx.x & 63;
  const int bx = th * 64;
  const int by = bx + 32;
  float s[2]; int id[2];
  #pragma unroll
  for (int r = 0; r < 2; ++r) {
    int sl = slot_ij[lane * 2 + r];
    if (sl != 0xFFFF) {
      s[r] = s1s[bx + (sl >> 5)] + s1s[by + (sl & 31)];
      id[r] = sl;
    } else {
      s[r] = -INFINITY; id[r] = 0x7fffffff;
    }
  }
  #define CE2(dd)                                                              \
    {                                                                          \
      bool sw = (dd) ? rank_before(s[0], id[0], s[1], id[1])                   \
                     : rank_before(s[1], id[1], s[0], id[0]);                  \
      if (sw) {                                                                \
        float ts = s[0]; s[0] = s[1]; s[1] = ts;                               \
        int ti = id[0]; id[0] = id[1]; id[1] = ti;                             \
      }                                                                        \
    }
  #define CROSS2(L, dd)                                                        \
    {                                                                          \
      bool amHigh = (lane & (L)) != 0;                                         \
      bool flip = amHigh != (dd);                                              \
      _Pragma("unroll")                                                        \
      for (int r = 0; r < 2; ++r) {                                            \
        float os = __shfl_xor(s[r], (L), 64);                                  \
        int oi = __shfl_xor(id[r], (L), 64);                                   \
        bool take = rank_before(os, oi, s[r], id[r]) != flip;                  \
        if (take) { s[r] = os; id[r] = oi; }                                   \
      }                                                                        \
    }
  { bool dd = (lane & 1) != 0; CE2(dd); }
  #pragma unroll
  for (int K = 4; K <= 128; K <<= 1) {
    bool dd = (lane & (K >> 1)) != 0;
    #pragma unroll
    for (int L = K >> 2; L >= 1; L >>= 1) CROSS2(L, dd);
    CE2(dd);
  }
  #undef CE2
  #undef CROSS2
  float smax = __shfl(s[0], 0, 64);
  float e0 = 0.f, e1 = 0.f;
  if (lane < 16) { e0 = expf(s[0] - smax); e1 = expf(s[1] - smax); }
  float part = e0 + e1;
  #pragma unroll
  for (int m = 1; m < 16; m <<= 1) part += __shfl_xor(part, m, 64);
  if (lane < 16) {
    int f0 = id[0], f1 = id[1];
    int vi0 = s1i[bx + (f0 >> 5)] * NKEYS + s1i[by + (f0 & 31)];
    int vi1 = s1i[bx + (f1 >> 5)] * NKEYS + s1i[by + (f1 & 31)];
    wgt[(size_t)th * KSEL + lane * 2] = e0 / part;
    wgt[(size_t)th * KSEL + lane * 2 + 1] = e1 / part;
    vidx[(size_t)th * KSEL + lane * 2] = vi0;
    vidx[(size_t)th * KSEL + lane * 2 + 1] = vi1;
  }
}

// ---------------- values fp32 -> bf16 (RNE) one-pass convert ----------------
__global__ __launch_bounds__(256) void convert_values(
    const float* __restrict__ values, unsigned int* __restrict__ vbf) {
  const size_t g = ((size_t)blockIdx.x * 256 + threadIdx.x) * 8;
  float4 a = *(const float4*)(values + g);
  float4 b = *(const float4*)(values + g + 4);
  uint4 pk;
  pk.x = f2bf(a.x) | (f2bf(a.y) << 16);
  pk.y = f2bf(a.z) | (f2bf(a.w) << 16);
  pk.z = f2bf(b.x) | (f2bf(b.y) << 16);
  pk.w = f2bf(b.z) | (f2bf(b.w) << 16);
  *(uint4*)(vbf + g / 2) = pk;
}

// ---------------- gather bf16: wave-per-row, 4 L3 phases ----------------
__global__ __launch_bounds__(256) void gather_bf16(
    const float* __restrict__ wgt, const int* __restrict__ vidx,
    const unsigned short* __restrict__ vbf, float* __restrict__ out) {
  const int t = blockIdx.x;
  const int tid = threadIdx.x, w = tid >> 6, lane = tid & 63;
  __shared__ float ws_[256];
  __shared__ int vs_[256];
  __shared__ float part[4 * 520];
  ws_[tid] = wgt[(size_t)t * 256 + tid];
  vs_[tid] = vidx[(size_t)t * 256 + tid];
  __syncthreads();
  float acc[8] = {};
  const int c0 = lane * 8;
  #pragma unroll 1
  for (int phase = 0; phase < 4; ++phase) {
    for (int e = w; e < 256; e += 4) {
      const int row = vs_[e];                 // wave-uniform scalar
      if ((row >> 14) != phase) continue;     // uniform branch, no divergence
      const float wv = ws_[e];
      uint4 pk = *(const uint4*)(vbf + (size_t)row * CDIM + c0);
      acc[0] += wv * bf2f(pk.x & 0xffff); acc[1] += wv * bf2f(pk.x >> 16);
      acc[2] += wv * bf2f(pk.y & 0xffff); acc[3] += wv * bf2f(pk.y >> 16);
      acc[4] += wv * bf2f(pk.z & 0xffff); acc[5] += wv * bf2f(pk.z >> 16);
      acc[6] += wv * bf2f(pk.w & 0xffff); acc[7] += wv * bf2f(pk.w >> 16);
    }
  }
  #pragma unroll
  for (int j = 0; j < 8; j += 4)
    *(float4*)&part[w * 520 + c0 + j] =
        make_float4(acc[j], acc[j + 1], acc[j + 2], acc[j + 3]);
  __syncthreads();
  const int c2 = tid * 2;
  float r0 = part[c2] + part[520 + c2] + part[1040 + c2] + part[1560 + c2];
  float r1 = part[c2 + 1] + part[520 + c2 + 1] + part[1040 + c2 + 1] + part[1560 + c2 + 1];
  *(float2*)(out + (size_t)t * CDIM + c2) = make_float2(r0, r1);
}

// ---------------- fallback fp32 gather (round-4, for small ws) ----------------
__global__ __launch_bounds__(256) void gather_kernel(
    const float* __restrict__ wgt, const int* __restrict__ vidx,
    const float* __restrict__ values, float* __restrict__ out) {
  const int tp = blockIdx.x;
  const int tid = threadIdx.x;
  __shared__ float ws_[512];
  __shared__ int vs_[512];
  ws_[tid] = wgt[(size_t)tp * 512 + tid];
  ws_[tid + 256] = wgt[(size_t)tp * 512 + tid + 256];
  vs_[tid] = vidx[(size_t)tp * 512 + tid];
  vs_[tid + 256] = vidx[(size_t)tp * 512 + tid + 256];
  __syncthreads();
  const int sub = tid >> 7;
  const int c4 = (tid & 127) * 4;
  const float* wp = &ws_[sub * 256];
  const int* vp = &vs_[sub * 256];
  float4 a = make_float4(0.f, 0.f, 0.f, 0.f);
  #pragma unroll 4
  for (int e = 0; e < 256; ++e) {
    float4 vv = *(const float4*)(values + (size_t)vp[e] * CDIM + c4);
    float wv = wp[e];
    a.x += wv * vv.x; a.y += wv * vv.y; a.z += wv * vv.z; a.w += wv * vv.w;
  }
  *(float4*)(out + (size_t)(tp * 2 + sub) * CDIM + c4) = a;
}

extern "C" void kernel_launch(void* const* d_in, const int* in_sizes, int n_in,
                              void* d_out, int out_size, void* d_ws, size_t ws_size,
                              hipStream_t stream) {
  const float* X      = (const float*)d_in[0];
  const float* W      = (const float*)d_in[1];
  const float* keys   = (const float*)d_in[2];
  const float* values = (const float*)d_in[3];
  const float* gamma  = (const float*)d_in[4];
  const float* beta   = (const float*)d_in[5];
  char* ws = (char*)d_ws;
  float* s1s = (float*)(ws);                  // 0..4 MB
  int*   s1i = (int*)  (ws + (4u << 20));     // 4..8 MB
  float* wgt = (float*)(ws + (8u << 20));     // 8..10 MB
  int*   vix = (int*)  (ws + (10u << 20));    // 10..12 MB
  float* Q   = (float*)(ws + (12u << 20));    // 12..28 MB (dead after dots_sel)
  float* kT  = (float*)(ws + (28u << 20));    // 28..30 MB (dead after dots_sel)
  unsigned int* vbf = (unsigned int*)(ws + (12u << 20));  // 12..76 MB (overlaps dead Q+kT)

  const bool bf16_path = ws_size >= (76u << 20);

  transpose_keys<<<dim3(16, 4), 256, 0, stream>>>(keys, kT);
  qgemm_ln<<<dim3(32, 16), 256, 0, stream>>>(X, W, gamma, beta, Q);
  dots_sel<<<dim3(16, 64), 512, 0, stream>>>(Q, kT, s1s, s1i);
  stage2_kernel<<<4096, 256, 0, stream>>>(s1s, s1i, wgt, vix);
  if (bf16_path) {
    convert_values<<<16384, 256, 0, stream>>>(values, vbf);  // after dots_sel: Q,kT dead
    gather_bf16<<<2048, 256, 0, stream>>>(wgt, vix, (const unsigned short*)vbf, (float*)d_out);
  } else {
    gather_kernel<<<1024, 256, 0, stream>>>(wgt, vix, values, (float*)d_out);
  }
}